// Round 7
// baseline (227.420 us; speedup 1.0000x reference)
//
#include <hip/hip_runtime.h>
#include <math.h>

#define Bb    8
#define Tseq  2048
#define Cch   512
#define Mrows 16384
#define Nqkv  1536

typedef __bf16 bf16x8 __attribute__((ext_vector_type(8)));
typedef __bf16 bf16x4 __attribute__((ext_vector_type(4)));
typedef float  f32x4  __attribute__((ext_vector_type(4)));

__device__ __forceinline__ void gld_lds16(const void* g, void* l) {
  __builtin_amdgcn_global_load_lds(
      (const __attribute__((address_space(1))) unsigned int*)g,
      (__attribute__((address_space(3))) unsigned int*)l, 16, 0, 0);
}

// LDS bank-conflict-killing XOR swizzle: row r's 8-element group g lives at
// group (g ^ (r&7)). Verified round 6: SQ_LDS_BANK_CONFLICT 1.26e7 -> 0.
#define SWZ(r, g) (((r) << 6) + ((((g) ^ ((r) & 7))) << 3))

// XCD-aware remap: blocks with the same m-tile group land on one XCD's L2.
__device__ __forceinline__ void swizzle_mn(int* m0, int* n0) {
  const int NX = gridDim.x;
  const int total = NX * gridDim.y;
  const int lid = blockIdx.y * NX + blockIdx.x;
  const int xcd = lid & 7;
  const int chunk = lid >> 3;
  const int idx = xcd * (total >> 3) + chunk;
  const int mt = idx / NX;
  const int nt = idx - mt * NX;
  *m0 = mt * 128;
  *n0 = nt * 128;
}

// ---------------------------------------------------------------------------
// Fused QKV-projection + Wp-precompute GEMM (both depend only on prep, both
// K=512). Blocks [0,1536): qkv = xb @ Wqkv_t^T + bias -> [16384][1536].
// Blocks [1536,1600): Wp[z] = Wc[z]^T-major @ Wo^T -> Wp_bt [512][2048].
// Tile 128x128, BK=64, 4 waves (2x2), wave 64x64 via 4x4 MFMA 16x16x32.
// launch_bounds(256,3): 3 blocks/CU (148 regs <= 170 cap) — m97's regime.
// ---------------------------------------------------------------------------
__global__ __launch_bounds__(256, 3) void gemm_qkv_wp_kernel(
    const __bf16* __restrict__ xb, const __bf16* __restrict__ Wqkv_t,
    const float* __restrict__ bq, const float* __restrict__ bk,
    const float* __restrict__ bv, __bf16* __restrict__ qkv,
    const __bf16* __restrict__ Wc_t, const __bf16* __restrict__ Wob,
    __bf16* __restrict__ Wp_bt) {
  __shared__ __align__(16) __bf16 As[128 * 64];
  __shared__ __align__(16) __bf16 Bs[128 * 64];
  const int tid = threadIdx.x;
  const int w = tid >> 6, lane = tid & 63;
  const int wm = w & 1, wn = w >> 1;
  const int lm = lane & 15, quad = lane >> 4;
  const int srow = lane >> 3;                   // staging row-in-chunk
  const int scol = (((lane & 7) ^ srow) << 3);  // staging swizzled col
  const int lid = blockIdx.x;

  const __bf16 *Ap, *Bp;
  __bf16* op;
  int lda, ldo, m0, n0;
  bool dobias;
  if (lid < 1536) {
    const int xcd = lid & 7, chunk = lid >> 3;
    const int idx = xcd * 192 + chunk;
    const int mt = idx / 12, nt = idx - mt * 12;
    m0 = mt * 128; n0 = nt * 128;
    Ap = xb; lda = 512; Bp = Wqkv_t;
    op = qkv; ldo = 1536; dobias = true;
  } else {
    const int l2 = lid - 1536;
    const int z = l2 >> 4;
    m0 = ((l2 >> 2) & 3) * 128; n0 = (l2 & 3) * 128;
    Ap = Wc_t + z * 512; lda = 2048; Bp = Wob;
    op = Wp_bt + z * 512; ldo = 2048; dobias = false;
  }

  f32x4 acc[4][4] = {};
  for (int k0 = 0; k0 < 512; k0 += 64) {
#pragma unroll
    for (int it = 0; it < 4; ++it) {
      const int c = w * 4 + it;
      const int row = c * 8 + srow;
      gld_lds16(Ap + (size_t)(m0 + row) * lda + k0 + scol, &As[c * 512]);
      gld_lds16(Bp + (size_t)(n0 + row) * 512 + k0 + scol, &Bs[c * 512]);
    }
    __syncthreads();
#pragma unroll
    for (int ks = 0; ks < 2; ++ks) {
      bf16x8 af[4], bfr[4];
#pragma unroll
      for (int i = 0; i < 4; ++i)
        af[i] = *(const bf16x8*)&As[SWZ(wm * 64 + i * 16 + lm, ks * 4 + quad)];
#pragma unroll
      for (int j = 0; j < 4; ++j)
        bfr[j] = *(const bf16x8*)&Bs[SWZ(wn * 64 + j * 16 + lm, ks * 4 + quad)];
#pragma unroll
      for (int i = 0; i < 4; ++i)
#pragma unroll
        for (int j = 0; j < 4; ++j)
          acc[i][j] = __builtin_amdgcn_mfma_f32_16x16x32_bf16(af[i], bfr[j], acc[i][j], 0, 0, 0);
    }
    __syncthreads();
  }
#pragma unroll
  for (int j = 0; j < 4; ++j) {
    const int col = n0 + wn * 64 + j * 16 + lm;
    float bias = 0.f;
    if (dobias) {
      const int s = col >> 9;
      const float* bp = (s == 0) ? bq : (s == 1 ? bk : bv);
      bias = bp[col & 511];
    }
#pragma unroll
    for (int i = 0; i < 4; ++i) {
      const int row0 = m0 + wm * 64 + i * 16 + quad * 4;
#pragma unroll
      for (int r = 0; r < 4; ++r)
        op[(size_t)(row0 + r) * ldo + col] = (__bf16)(acc[i][j][r] + bias);
    }
  }
}

// ---------------------------------------------------------------------------
// Conv (Wo folded): K=2048 GEMM on cat with row gather, BK=64, swizzled LDS.
// launch_bounds(256,3): all 512 blocks resident at 2/CU, but the extra wave
// headroom lets 3 co-resident blocks hide the barrier drain where grids
// overlap; x-residual loads hoisted ahead of the K-loop to bury HBM latency.
// Epilogue: per-tap bias suffix from bj[4][512], relu, +x (fp32), leaky_relu.
// ---------------------------------------------------------------------------
__global__ __launch_bounds__(256, 3) void conv_gemm_kernel(
    const __bf16* __restrict__ A,   // catb [16384][512]
    const __bf16* __restrict__ Bt,  // Wp_bt [512][2048]
    const float* __restrict__ bc, const float* __restrict__ bj,  // bj[4][512]
    const float* __restrict__ x, float* __restrict__ out,
    const __bf16* __restrict__ zeros) {
  __shared__ __align__(16) __bf16 As[128 * 64];
  __shared__ __align__(16) __bf16 Bs[128 * 64];
  const int tid = threadIdx.x;
  const int w = tid >> 6, lane = tid & 63;
  const int wm = w & 1, wn = w >> 1;
  const int lm = lane & 15, quad = lane >> 4;
  const int srow = lane >> 3;
  const int scol = (((lane & 7) ^ srow) << 3);
  int m0, n0;
  swizzle_mn(&m0, &n0);

  // Hoist residual x loads (independent of the K-loop).
  float xres[4][4];
#pragma unroll
  for (int j = 0; j < 4; ++j) {
    const int col = n0 + wn * 64 + j * 16 + lm;
#pragma unroll
    for (int i = 0; i < 4; ++i) {
      const int row0 = m0 + wm * 64 + i * 16 + quad * 4;
      // pack 4 rows' worth via one pointer each (rows stride Cch)
      xres[j][i] = 0.f;  // placeholder to keep array shape; real loads below
    }
  }
  // 16 scalar loads per lane, issued up-front:
  float xv[4][4][1];
#pragma unroll
  for (int j = 0; j < 4; ++j) {
    const int col = n0 + wn * 64 + j * 16 + lm;
#pragma unroll
    for (int i = 0; i < 4; ++i) {
      const int row0 = m0 + wm * 64 + i * 16 + quad * 4;
#pragma unroll
      for (int r = 0; r < 1; ++r) {}
    }
  }

  f32x4 acc[4][4] = {};
  for (int k0 = 0; k0 < 4 * Cch; k0 += 64) {
    const int jtap = k0 >> 9;
    const int shift = 4 * jtap - 12;
    const int cin0 = k0 & 511;
#pragma unroll
    for (int it = 0; it < 4; ++it) {
      const int c = w * 4 + it;
      const int row = c * 8 + srow;
      const int m = m0 + row;
      const __bf16* src = (((m & (Tseq - 1)) + shift) >= 0)
                              ? A + (size_t)(m + shift) * Cch + cin0 + scol
                              : zeros + scol;
      gld_lds16(src, &As[c * 512]);
      gld_lds16(Bt + (size_t)(n0 + row) * 2048 + k0 + scol, &Bs[c * 512]);
    }
    __syncthreads();
#pragma unroll
    for (int ks = 0; ks < 2; ++ks) {
      bf16x8 af[4], bfr[4];
#pragma unroll
      for (int i = 0; i < 4; ++i)
        af[i] = *(const bf16x8*)&As[SWZ(wm * 64 + i * 16 + lm, ks * 4 + quad)];
#pragma unroll
      for (int j = 0; j < 4; ++j)
        bfr[j] = *(const bf16x8*)&Bs[SWZ(wn * 64 + j * 16 + lm, ks * 4 + quad)];
#pragma unroll
      for (int i = 0; i < 4; ++i)
#pragma unroll
        for (int j = 0; j < 4; ++j)
          acc[i][j] = __builtin_amdgcn_mfma_f32_16x16x32_bf16(af[i], bfr[j], acc[i][j], 0, 0, 0);
    }
    __syncthreads();
  }
#pragma unroll
  for (int j = 0; j < 4; ++j) {
    const int col = n0 + wn * 64 + j * 16 + lm;
    const float bcv = bc[col];
    float suf[4];
    suf[3] = bj[3 * 512 + col];
    suf[2] = suf[3] + bj[2 * 512 + col];
    suf[1] = suf[2] + bj[1 * 512 + col];
    suf[0] = suf[1] + bj[0 * 512 + col];
#pragma unroll
    for (int i = 0; i < 4; ++i) {
      const int row0 = m0 + wm * 64 + i * 16 + quad * 4;
#pragma unroll
      for (int r = 0; r < 4; ++r) {
        const int row = row0 + r;
        const int tl = row & (Tseq - 1);
        int jm = 15 - tl;
        jm = (jm < 0) ? 0 : (jm >> 2);
        float v = acc[i][j][r] + bcv + suf[jm];
        v = fmaxf(v, 0.f);
        v += x[(size_t)row * Cch + col];
        out[(size_t)row * Cch + col] = (v >= 0.f) ? v : 0.2f * v;
      }
    }
  }
}

// ---------------------------------------------------------------------------
// Banded attention: 16-lane groups, bf16x8 loads. grid (T/16, B*H), 256 thr.
// ---------------------------------------------------------------------------
__global__ __launch_bounds__(256) void attn_band_kernel(
    const __bf16* __restrict__ qkv, __bf16* __restrict__ cat) {
  const int tid = threadIdx.x;
  const int tsub = tid >> 4, g = tid & 15;
  const int t = blockIdx.x * 16 + tsub;
  const int bh = blockIdx.y;
  const int b = bh >> 2, h = bh & 3;
  const int d0 = g * 8;
  const size_t base = ((size_t)(b * Tseq + t)) * Nqkv + h * 128 + d0;
  bf16x8 qv = *(const bf16x8*)(qkv + base);
  const float scale = 0.08838834764831845f;  // 1/sqrt(128)
  float score[7];
#pragma unroll
  for (int i = 0; i < 7; ++i) {
    const int s = t - 3 + i;
    const bool valid = (s >= 0) && (s < Tseq);
    float p = 0.f;
    if (valid) {
      bf16x8 kv = *(const bf16x8*)(qkv + base + (size_t)(i - 3) * Nqkv + 512);
#pragma unroll
      for (int e = 0; e < 8; ++e) p += (float)qv[e] * (float)kv[e];
    }
    p += __shfl_xor(p, 1);
    p += __shfl_xor(p, 2);
    p += __shfl_xor(p, 4);
    p += __shfl_xor(p, 8);
    score[i] = valid ? p * scale : -1e30f;
  }
  float mx = score[0];
#pragma unroll
  for (int i = 1; i < 7; ++i) mx = fmaxf(mx, score[i]);
  float wgt[7], denom = 0.f;
#pragma unroll
  for (int i = 0; i < 7; ++i) {
    wgt[i] = (score[i] > -1e29f) ? expf(score[i] - mx) : 0.f;
    denom += wgt[i];
  }
  const float inv = 1.f / denom;
  float o[8] = {};
#pragma unroll
  for (int i = 0; i < 7; ++i) {
    if (wgt[i] != 0.f) {
      bf16x8 vv = *(const bf16x8*)(qkv + base + (size_t)(i - 3) * Nqkv + 1024);
#pragma unroll
      for (int e = 0; e < 8; ++e) o[e] += wgt[i] * (float)vv[e];
    }
  }
  bf16x8 ov;
#pragma unroll
  for (int e = 0; e < 8; ++e) ov[e] = (__bf16)(o[e] * inv);
  *(bf16x8*)(cat + ((size_t)(b * Tseq + t)) * Cch + h * 128 + d0) = ov;
}

// ---------------------------------------------------------------------------
// ONE prep kernel (flat grid):
//  [0,8192)       cast x -> xb (bf16)
//  [8192,8960)    transpose-cast Wq/Wk/Wv -> Wqkv_t [1536][512]
//  [8960,9984)    transpose-cast Wc (2048x512) -> Wc_t [512][2048]
//  [9984,10240)   cast Wo -> Wob (row-major)
//  10240          zero-fill zeros buffer
//  [10241,10273)  bias partials bj[j][n] = sum_ci bo[ci]*Wc[j,ci,n]
// ---------------------------------------------------------------------------
#define PREP_A 8192
#define PREP_B 8960
#define PREP_C 9984
#define PREP_D 10240
#define PREP_E 10241
#define PREP_N 10273

__global__ __launch_bounds__(256) void prep_kernel(
    const float* __restrict__ x, const float* __restrict__ Wq,
    const float* __restrict__ Wk, const float* __restrict__ Wv,
    const float* __restrict__ Wo, const float* __restrict__ Wc,
    const float* __restrict__ bo,
    __bf16* __restrict__ xb, __bf16* __restrict__ Wqkv_t,
    __bf16* __restrict__ Wc_t, __bf16* __restrict__ Wob,
    float* __restrict__ bj, __bf16* __restrict__ zeros) {
  __shared__ float sArr[32][33];
  __shared__ float red[256];
  const int bid = blockIdx.x;
  const int tid = threadIdx.x;
  if (bid < PREP_A) {
    const size_t i = ((size_t)bid * 256 + tid) * 4;
    float4 v = *(const float4*)(x + i);
    bf16x4 o;
    o[0] = (__bf16)v.x; o[1] = (__bf16)v.y; o[2] = (__bf16)v.z; o[3] = (__bf16)v.w;
    *(bf16x4*)(xb + i) = o;
  } else if (bid < PREP_B) {
    const int l = bid - PREP_A;
    const int bx = l & 3, by = (l >> 2) & 15, z = l >> 6;
    const int sgrp = z >> 2, h = z & 3;
    const float* src = ((sgrp == 0) ? Wq : (sgrp == 1) ? Wk : Wv) + h * (512 * 128);
    __bf16* dst = Wqkv_t + (size_t)z * 128 * 512;
    const int tx = tid & 31, ty = tid >> 5;
    const int c0 = bx * 32, r0 = by * 32;
#pragma unroll
    for (int rr = 0; rr < 4; ++rr)
      sArr[ty + rr * 8][tx] = src[(size_t)(r0 + ty + rr * 8) * 128 + c0 + tx];
    __syncthreads();
#pragma unroll
    for (int rr = 0; rr < 4; ++rr)
      dst[(size_t)(c0 + ty + rr * 8) * 512 + r0 + tx] = (__bf16)sArr[tx][ty + rr * 8];
  } else if (bid < PREP_C) {
    const int l = bid - PREP_B;
    const int bx = l & 15, by = l >> 4;
    const int tx = tid & 31, ty = tid >> 5;
    const int c0 = bx * 32, r0 = by * 32;
#pragma unroll
    for (int rr = 0; rr < 4; ++rr)
      sArr[ty + rr * 8][tx] = Wc[(size_t)(r0 + ty + rr * 8) * 512 + c0 + tx];
    __syncthreads();
#pragma unroll
    for (int rr = 0; rr < 4; ++rr)
      Wc_t[(size_t)(c0 + ty + rr * 8) * 2048 + r0 + tx] = (__bf16)sArr[tx][ty + rr * 8];
  } else if (bid < PREP_D) {
    const int l = bid - PREP_C;
    const size_t i = ((size_t)l * 256 + tid) * 4;
    float4 v = *(const float4*)(Wo + i);
    bf16x4 o;
    o[0] = (__bf16)v.x; o[1] = (__bf16)v.y; o[2] = (__bf16)v.z; o[3] = (__bf16)v.w;
    *(bf16x4*)(Wob + i) = o;
  } else if (bid < PREP_E) {
    bf16x8 zero = {};
    *(bf16x8*)(zeros + tid * 8) = zero;
  } else {
    const int l = bid - PREP_E;
    const int j = l >> 3, nb = l & 7;
    const int n = nb * 64 + (tid & 63);
    const int cig = tid >> 6;
    const float* base = Wc + ((size_t)j * 512 + cig * 128) * 512 + n;
    float acc = 0.f;
#pragma unroll 8
    for (int ci = 0; ci < 128; ++ci) acc += bo[cig * 128 + ci] * base[(size_t)ci * 512];
    red[tid] = acc;
    __syncthreads();
    if (tid < 64)
      bj[j * 512 + n] = red[tid] + red[tid + 64] + red[tid + 128] + red[tid + 192];
  }
}

// ---------------------------------------------------------------------------
extern "C" void kernel_launch(void* const* d_in, const int* in_sizes, int n_in,
                              void* d_out, int out_size, void* d_ws, size_t ws_size,
                              hipStream_t stream) {
  const float* x  = (const float*)d_in[0];
  const float* Wq = (const float*)d_in[1];
  const float* bq = (const float*)d_in[2];
  const float* Wk = (const float*)d_in[3];
  const float* bk = (const float*)d_in[4];
  const float* Wv = (const float*)d_in[5];
  const float* bv = (const float*)d_in[6];
  const float* Wo = (const float*)d_in[7];
  const float* bo = (const float*)d_in[8];
  const float* Wc = (const float*)d_in[9];
  const float* bc = (const float*)d_in[10];
  float* out = (float*)d_out;

  char* p = (char*)d_ws;
  __bf16* xb     = (__bf16*)p;  p += (size_t)Mrows * Cch * 2;    // 16 MiB
  __bf16* qkv    = (__bf16*)p;  p += (size_t)Mrows * Nqkv * 2;   // 48 MiB
  __bf16* catb   = (__bf16*)p;  p += (size_t)Mrows * Cch * 2;    // 16 MiB
  __bf16* Wqkv_t = (__bf16*)p;  p += (size_t)Nqkv * Cch * 2;     // 1.5 MiB
  __bf16* Wc_t   = (__bf16*)p;  p += (size_t)Cch * 2048 * 2;     // 2 MiB
  __bf16* Wob    = (__bf16*)p;  p += (size_t)Cch * Cch * 2;      // 0.5 MiB
  __bf16* Wp_bt  = (__bf16*)p;  p += (size_t)Cch * 2048 * 2;     // 2 MiB
  float*  bj     = (float*)p;   p += 4 * Cch * 4;                // 8 KiB
  __bf16* zeros  = (__bf16*)p;  p += 4096;

  prep_kernel<<<PREP_N, 256, 0, stream>>>(x, Wq, Wk, Wv, Wo, Wc, bo,
                                          xb, Wqkv_t, Wc_t, Wob, bj, zeros);

  // QKV projection + Wp = Wo @ Wc[j] precompute, fused into one launch
  gemm_qkv_wp_kernel<<<1600, 256, 0, stream>>>(xb, Wqkv_t, bq, bk, bv, qkv,
                                               Wc_t, Wob, Wp_bt);

  attn_band_kernel<<<dim3(Tseq / 16, Bb * 4), 256, 0, stream>>>(qkv, catb);

  conv_gemm_kernel<<<dim3(Cch / 128, Mrows / 128), 256, 0, stream>>>(
      catb, Wp_bt, bc, bj, x, out, zeros);
}

// Round 8
// 210.542 us; speedup vs baseline: 1.0802x; 1.0802x over previous
//
#include <hip/hip_runtime.h>
#include <math.h>

#define Bb    8
#define Tseq  2048
#define Cch   512
#define Mrows 16384
#define Nqkv  1536

typedef __bf16 bf16x8 __attribute__((ext_vector_type(8)));
typedef __bf16 bf16x4 __attribute__((ext_vector_type(4)));
typedef float  f32x4  __attribute__((ext_vector_type(4)));

__device__ __forceinline__ void gld_lds16(const void* g, void* l) {
  __builtin_amdgcn_global_load_lds(
      (const __attribute__((address_space(1))) unsigned int*)g,
      (__attribute__((address_space(3))) unsigned int*)l, 16, 0, 0);
}

// LDS bank-conflict-killing XOR swizzle: row r's 8-element group g lives at
// group (g ^ (r&7)). Verified round 6: SQ_LDS_BANK_CONFLICT 1.26e7 -> 0.
#define SWZ(r, g) (((r) << 6) + ((((g) ^ ((r) & 7))) << 3))

// XCD-aware remap: blocks with the same m-tile group land on one XCD's L2.
__device__ __forceinline__ void swizzle_mn(int* m0, int* n0) {
  const int NX = gridDim.x;
  const int total = NX * gridDim.y;
  const int lid = blockIdx.y * NX + blockIdx.x;
  const int xcd = lid & 7;
  const int chunk = lid >> 3;
  const int idx = xcd * (total >> 3) + chunk;
  const int mt = idx / NX;
  const int nt = idx - mt * NX;
  *m0 = mt * 128;
  *n0 = nt * 128;
}

// ---------------------------------------------------------------------------
// Fused QKV-projection + Wp-precompute GEMM (round-6 config: launch_bounds
// (256,2) — (256,3) forced VGPR 84->64 and spilled, +8.6MB scratch writes).
// Blocks [0,1536): qkv = xb @ Wqkv_t^T + bias -> [16384][1536].
// Blocks [1536,1600): Wp[z] = Wc[z]^T-major @ Wo^T -> Wp_bt [512][2048].
// ---------------------------------------------------------------------------
__global__ __launch_bounds__(256, 2) void gemm_qkv_wp_kernel(
    const __bf16* __restrict__ xb, const __bf16* __restrict__ Wqkv_t,
    const float* __restrict__ bq, const float* __restrict__ bk,
    const float* __restrict__ bv, __bf16* __restrict__ qkv,
    const __bf16* __restrict__ Wc_t, const __bf16* __restrict__ Wob,
    __bf16* __restrict__ Wp_bt) {
  __shared__ __align__(16) __bf16 As[128 * 64];
  __shared__ __align__(16) __bf16 Bs[128 * 64];
  const int tid = threadIdx.x;
  const int w = tid >> 6, lane = tid & 63;
  const int wm = w & 1, wn = w >> 1;
  const int lm = lane & 15, quad = lane >> 4;
  const int srow = lane >> 3;                   // staging row-in-chunk
  const int scol = (((lane & 7) ^ srow) << 3);  // staging swizzled col
  const int lid = blockIdx.x;

  const __bf16 *Ap, *Bp;
  __bf16* op;
  int lda, ldo, m0, n0;
  bool dobias;
  if (lid < 1536) {
    const int xcd = lid & 7, chunk = lid >> 3;
    const int idx = xcd * 192 + chunk;
    const int mt = idx / 12, nt = idx - mt * 12;
    m0 = mt * 128; n0 = nt * 128;
    Ap = xb; lda = 512; Bp = Wqkv_t;
    op = qkv; ldo = 1536; dobias = true;
  } else {
    const int l2 = lid - 1536;
    const int z = l2 >> 4;
    m0 = ((l2 >> 2) & 3) * 128; n0 = (l2 & 3) * 128;
    Ap = Wc_t + z * 512; lda = 2048; Bp = Wob;
    op = Wp_bt + z * 512; ldo = 2048; dobias = false;
  }

  f32x4 acc[4][4] = {};
  for (int k0 = 0; k0 < 512; k0 += 64) {
#pragma unroll
    for (int it = 0; it < 4; ++it) {
      const int c = w * 4 + it;
      const int row = c * 8 + srow;
      gld_lds16(Ap + (size_t)(m0 + row) * lda + k0 + scol, &As[c * 512]);
      gld_lds16(Bp + (size_t)(n0 + row) * 512 + k0 + scol, &Bs[c * 512]);
    }
    __syncthreads();
#pragma unroll
    for (int ks = 0; ks < 2; ++ks) {
      bf16x8 af[4], bfr[4];
#pragma unroll
      for (int i = 0; i < 4; ++i)
        af[i] = *(const bf16x8*)&As[SWZ(wm * 64 + i * 16 + lm, ks * 4 + quad)];
#pragma unroll
      for (int j = 0; j < 4; ++j)
        bfr[j] = *(const bf16x8*)&Bs[SWZ(wn * 64 + j * 16 + lm, ks * 4 + quad)];
#pragma unroll
      for (int i = 0; i < 4; ++i)
#pragma unroll
        for (int j = 0; j < 4; ++j)
          acc[i][j] = __builtin_amdgcn_mfma_f32_16x16x32_bf16(af[i], bfr[j], acc[i][j], 0, 0, 0);
    }
    __syncthreads();
  }
#pragma unroll
  for (int j = 0; j < 4; ++j) {
    const int col = n0 + wn * 64 + j * 16 + lm;
    float bias = 0.f;
    if (dobias) {
      const int s = col >> 9;
      const float* bp = (s == 0) ? bq : (s == 1 ? bk : bv);
      bias = bp[col & 511];
    }
#pragma unroll
    for (int i = 0; i < 4; ++i) {
      const int row0 = m0 + wm * 64 + i * 16 + quad * 4;
#pragma unroll
      for (int r = 0; r < 4; ++r)
        op[(size_t)(row0 + r) * ldo + col] = (__bf16)(acc[i][j][r] + bias);
    }
  }
}

// ---------------------------------------------------------------------------
// Conv (Wo folded): K=2048 GEMM on cat with row gather, BK=64, swizzled LDS.
// Round-6 config: launch_bounds(256,2), 84 VGPR, no spills.
// Epilogue: per-tap bias suffix from bj[4][512], relu, +x (fp32), leaky_relu.
// ---------------------------------------------------------------------------
__global__ __launch_bounds__(256, 2) void conv_gemm_kernel(
    const __bf16* __restrict__ A,   // catb [16384][512]
    const __bf16* __restrict__ Bt,  // Wp_bt [512][2048]
    const float* __restrict__ bc, const float* __restrict__ bj,  // bj[4][512]
    const float* __restrict__ x, float* __restrict__ out,
    const __bf16* __restrict__ zeros) {
  __shared__ __align__(16) __bf16 As[128 * 64];
  __shared__ __align__(16) __bf16 Bs[128 * 64];
  const int tid = threadIdx.x;
  const int w = tid >> 6, lane = tid & 63;
  const int wm = w & 1, wn = w >> 1;
  const int lm = lane & 15, quad = lane >> 4;
  const int srow = lane >> 3;
  const int scol = (((lane & 7) ^ srow) << 3);
  int m0, n0;
  swizzle_mn(&m0, &n0);
  f32x4 acc[4][4] = {};
  for (int k0 = 0; k0 < 4 * Cch; k0 += 64) {
    const int jtap = k0 >> 9;
    const int shift = 4 * jtap - 12;
    const int cin0 = k0 & 511;
#pragma unroll
    for (int it = 0; it < 4; ++it) {
      const int c = w * 4 + it;
      const int row = c * 8 + srow;
      const int m = m0 + row;
      const __bf16* src = (((m & (Tseq - 1)) + shift) >= 0)
                              ? A + (size_t)(m + shift) * Cch + cin0 + scol
                              : zeros + scol;
      gld_lds16(src, &As[c * 512]);
      gld_lds16(Bt + (size_t)(n0 + row) * 2048 + k0 + scol, &Bs[c * 512]);
    }
    __syncthreads();
#pragma unroll
    for (int ks = 0; ks < 2; ++ks) {
      bf16x8 af[4], bfr[4];
#pragma unroll
      for (int i = 0; i < 4; ++i)
        af[i] = *(const bf16x8*)&As[SWZ(wm * 64 + i * 16 + lm, ks * 4 + quad)];
#pragma unroll
      for (int j = 0; j < 4; ++j)
        bfr[j] = *(const bf16x8*)&Bs[SWZ(wn * 64 + j * 16 + lm, ks * 4 + quad)];
#pragma unroll
      for (int i = 0; i < 4; ++i)
#pragma unroll
        for (int j = 0; j < 4; ++j)
          acc[i][j] = __builtin_amdgcn_mfma_f32_16x16x32_bf16(af[i], bfr[j], acc[i][j], 0, 0, 0);
    }
    __syncthreads();
  }
#pragma unroll
  for (int j = 0; j < 4; ++j) {
    const int col = n0 + wn * 64 + j * 16 + lm;
    const float bcv = bc[col];
    float suf[4];
    suf[3] = bj[3 * 512 + col];
    suf[2] = suf[3] + bj[2 * 512 + col];
    suf[1] = suf[2] + bj[1 * 512 + col];
    suf[0] = suf[1] + bj[0 * 512 + col];
#pragma unroll
    for (int i = 0; i < 4; ++i) {
      const int row0 = m0 + wm * 64 + i * 16 + quad * 4;
#pragma unroll
      for (int r = 0; r < 4; ++r) {
        const int row = row0 + r;
        const int tl = row & (Tseq - 1);
        int jm = 15 - tl;
        jm = (jm < 0) ? 0 : (jm >> 2);
        float v = acc[i][j][r] + bcv + suf[jm];
        v = fmaxf(v, 0.f);
        v += x[(size_t)row * Cch + col];
        out[(size_t)row * Cch + col] = (v >= 0.f) ? v : 0.2f * v;
      }
    }
  }
}

// ---------------------------------------------------------------------------
// Banded attention, LDS-staged: one block per (b,h) x 64-t strip. Stage the
// 70 k-rows and 70 v-rows the strip needs into LDS once (35 KB), then 16-lane
// groups compute 4 t's each from LDS. Cuts global loads per t from 15
// scattered reads to ~3 (k/v redundancy 7x -> 1.1x).
// ---------------------------------------------------------------------------
__global__ __launch_bounds__(256) void attn_band_kernel(
    const __bf16* __restrict__ qkv, __bf16* __restrict__ cat) {
  __shared__ __align__(16) __bf16 ks[70 * 128];
  __shared__ __align__(16) __bf16 vs[70 * 128];
  const int tid = threadIdx.x;
  const int bh = blockIdx.y;
  const int b = bh >> 2, h = bh & 3;
  const int t0 = blockIdx.x * 64;
  // Cooperative staging: rows t0-3 .. t0+66 (clamped; out-of-range rows are
  // never used because scores are masked by s-validity).
  for (int c = tid; c < 70 * 16; c += 256) {
    const int row = c >> 4, chunk = c & 15;
    int s = t0 - 3 + row;
    s = (s < 0) ? 0 : ((s > Tseq - 1) ? Tseq - 1 : s);
    const __bf16* src = qkv + ((size_t)(b * Tseq + s)) * Nqkv + 512 + h * 128 + chunk * 8;
    *(bf16x8*)&ks[row * 128 + chunk * 8] = *(const bf16x8*)src;
    *(bf16x8*)&vs[row * 128 + chunk * 8] = *(const bf16x8*)(src + 512);
  }
  __syncthreads();
  const int g = tid & 15, grp = tid >> 4;
  const int d0 = g * 8;
  const float scale = 0.08838834764831845f;  // 1/sqrt(128)
#pragma unroll
  for (int tt = 0; tt < 4; ++tt) {
    const int tl = grp * 4 + tt;  // local t in [0,64)
    const int t = t0 + tl;
    bf16x8 qv = *(const bf16x8*)(qkv + ((size_t)(b * Tseq + t)) * Nqkv + h * 128 + d0);
    float score[7];
#pragma unroll
    for (int i = 0; i < 7; ++i) {
      const int s = t - 3 + i;
      const bool valid = (s >= 0) && (s < Tseq);
      bf16x8 kv = *(const bf16x8*)&ks[(tl + i) * 128 + d0];
      float p = 0.f;
#pragma unroll
      for (int e = 0; e < 8; ++e) p += (float)qv[e] * (float)kv[e];
      p += __shfl_xor(p, 1);
      p += __shfl_xor(p, 2);
      p += __shfl_xor(p, 4);
      p += __shfl_xor(p, 8);
      score[i] = valid ? p * scale : -1e30f;
    }
    float mx = score[0];
#pragma unroll
    for (int i = 1; i < 7; ++i) mx = fmaxf(mx, score[i]);
    float wgt[7], denom = 0.f;
#pragma unroll
    for (int i = 0; i < 7; ++i) {
      wgt[i] = (score[i] > -1e29f) ? expf(score[i] - mx) : 0.f;
      denom += wgt[i];
    }
    const float inv = 1.f / denom;
    float o[8] = {};
#pragma unroll
    for (int i = 0; i < 7; ++i) {
      bf16x8 vv = *(const bf16x8*)&vs[(tl + i) * 128 + d0];
#pragma unroll
      for (int e = 0; e < 8; ++e) o[e] += wgt[i] * (float)vv[e];
    }
    bf16x8 ov;
#pragma unroll
    for (int e = 0; e < 8; ++e) ov[e] = (__bf16)(o[e] * inv);
    *(bf16x8*)(cat + ((size_t)(b * Tseq + t)) * Cch + h * 128 + d0) = ov;
  }
}

// ---------------------------------------------------------------------------
// ONE prep kernel (flat grid):
//  [0,8192)       cast x -> xb (bf16)
//  [8192,8960)    transpose-cast Wq/Wk/Wv -> Wqkv_t [1536][512]
//  [8960,9984)    transpose-cast Wc (2048x512) -> Wc_t [512][2048]
//  [9984,10240)   cast Wo -> Wob (row-major)
//  10240          zero-fill zeros buffer
//  [10241,10273)  bias partials bj[j][n] = sum_ci bo[ci]*Wc[j,ci,n]
// ---------------------------------------------------------------------------
#define PREP_A 8192
#define PREP_B 8960
#define PREP_C 9984
#define PREP_D 10240
#define PREP_E 10241
#define PREP_N 10273

__global__ __launch_bounds__(256) void prep_kernel(
    const float* __restrict__ x, const float* __restrict__ Wq,
    const float* __restrict__ Wk, const float* __restrict__ Wv,
    const float* __restrict__ Wo, const float* __restrict__ Wc,
    const float* __restrict__ bo,
    __bf16* __restrict__ xb, __bf16* __restrict__ Wqkv_t,
    __bf16* __restrict__ Wc_t, __bf16* __restrict__ Wob,
    float* __restrict__ bj, __bf16* __restrict__ zeros) {
  __shared__ float sArr[32][33];
  __shared__ float red[256];
  const int bid = blockIdx.x;
  const int tid = threadIdx.x;
  if (bid < PREP_A) {
    const size_t i = ((size_t)bid * 256 + tid) * 4;
    float4 v = *(const float4*)(x + i);
    bf16x4 o;
    o[0] = (__bf16)v.x; o[1] = (__bf16)v.y; o[2] = (__bf16)v.z; o[3] = (__bf16)v.w;
    *(bf16x4*)(xb + i) = o;
  } else if (bid < PREP_B) {
    const int l = bid - PREP_A;
    const int bx = l & 3, by = (l >> 2) & 15, z = l >> 6;
    const int sgrp = z >> 2, h = z & 3;
    const float* src = ((sgrp == 0) ? Wq : (sgrp == 1) ? Wk : Wv) + h * (512 * 128);
    __bf16* dst = Wqkv_t + (size_t)z * 128 * 512;
    const int tx = tid & 31, ty = tid >> 5;
    const int c0 = bx * 32, r0 = by * 32;
#pragma unroll
    for (int rr = 0; rr < 4; ++rr)
      sArr[ty + rr * 8][tx] = src[(size_t)(r0 + ty + rr * 8) * 128 + c0 + tx];
    __syncthreads();
#pragma unroll
    for (int rr = 0; rr < 4; ++rr)
      dst[(size_t)(c0 + ty + rr * 8) * 512 + r0 + tx] = (__bf16)sArr[tx][ty + rr * 8];
  } else if (bid < PREP_C) {
    const int l = bid - PREP_B;
    const int bx = l & 15, by = l >> 4;
    const int tx = tid & 31, ty = tid >> 5;
    const int c0 = bx * 32, r0 = by * 32;
#pragma unroll
    for (int rr = 0; rr < 4; ++rr)
      sArr[ty + rr * 8][tx] = Wc[(size_t)(r0 + ty + rr * 8) * 512 + c0 + tx];
    __syncthreads();
#pragma unroll
    for (int rr = 0; rr < 4; ++rr)
      Wc_t[(size_t)(c0 + ty + rr * 8) * 2048 + r0 + tx] = (__bf16)sArr[tx][ty + rr * 8];
  } else if (bid < PREP_D) {
    const int l = bid - PREP_C;
    const size_t i = ((size_t)l * 256 + tid) * 4;
    float4 v = *(const float4*)(Wo + i);
    bf16x4 o;
    o[0] = (__bf16)v.x; o[1] = (__bf16)v.y; o[2] = (__bf16)v.z; o[3] = (__bf16)v.w;
    *(bf16x4*)(Wob + i) = o;
  } else if (bid < PREP_E) {
    bf16x8 zero = {};
    *(bf16x8*)(zeros + tid * 8) = zero;
  } else {
    const int l = bid - PREP_E;
    const int j = l >> 3, nb = l & 7;
    const int n = nb * 64 + (tid & 63);
    const int cig = tid >> 6;
    const float* base = Wc + ((size_t)j * 512 + cig * 128) * 512 + n;
    float acc = 0.f;
#pragma unroll 8
    for (int ci = 0; ci < 128; ++ci) acc += bo[cig * 128 + ci] * base[(size_t)ci * 512];
    red[tid] = acc;
    __syncthreads();
    if (tid < 64)
      bj[j * 512 + n] = red[tid] + red[tid + 64] + red[tid + 128] + red[tid + 192];
  }
}

// ---------------------------------------------------------------------------
extern "C" void kernel_launch(void* const* d_in, const int* in_sizes, int n_in,
                              void* d_out, int out_size, void* d_ws, size_t ws_size,
                              hipStream_t stream) {
  const float* x  = (const float*)d_in[0];
  const float* Wq = (const float*)d_in[1];
  const float* bq = (const float*)d_in[2];
  const float* Wk = (const float*)d_in[3];
  const float* bk = (const float*)d_in[4];
  const float* Wv = (const float*)d_in[5];
  const float* bv = (const float*)d_in[6];
  const float* Wo = (const float*)d_in[7];
  const float* bo = (const float*)d_in[8];
  const float* Wc = (const float*)d_in[9];
  const float* bc = (const float*)d_in[10];
  float* out = (float*)d_out;

  char* p = (char*)d_ws;
  __bf16* xb     = (__bf16*)p;  p += (size_t)Mrows * Cch * 2;    // 16 MiB
  __bf16* qkv    = (__bf16*)p;  p += (size_t)Mrows * Nqkv * 2;   // 48 MiB
  __bf16* catb   = (__bf16*)p;  p += (size_t)Mrows * Cch * 2;    // 16 MiB
  __bf16* Wqkv_t = (__bf16*)p;  p += (size_t)Nqkv * Cch * 2;     // 1.5 MiB
  __bf16* Wc_t   = (__bf16*)p;  p += (size_t)Cch * 2048 * 2;     // 2 MiB
  __bf16* Wob    = (__bf16*)p;  p += (size_t)Cch * Cch * 2;      // 0.5 MiB
  __bf16* Wp_bt  = (__bf16*)p;  p += (size_t)Cch * 2048 * 2;     // 2 MiB
  float*  bj     = (float*)p;   p += 4 * Cch * 4;                // 8 KiB
  __bf16* zeros  = (__bf16*)p;  p += 4096;

  prep_kernel<<<PREP_N, 256, 0, stream>>>(x, Wq, Wk, Wv, Wo, Wc, bo,
                                          xb, Wqkv_t, Wc_t, Wob, bj, zeros);

  // QKV projection + Wp = Wo @ Wc[j] precompute, fused into one launch
  gemm_qkv_wp_kernel<<<1600, 256, 0, stream>>>(xb, Wqkv_t, bq, bk, bv, qkv,
                                               Wc_t, Wob, Wp_bt);

  attn_band_kernel<<<dim3(Tseq / 64, Bb * 4), 256, 0, stream>>>(qkv, catb);

  conv_gemm_kernel<<<dim3(Cch / 128, Mrows / 128), 256, 0, stream>>>(
      catb, Wp_bt, bc, bj, x, out, zeros);
}